// Round 1
// baseline (72.975 us; speedup 1.0000x reference)
//
#include <hip/hip_runtime.h>

#define DIM 16
#define NQ 4
#define NL 3
#define VQC_BATCH 524288

// clang ext-vector float2 -> legalizes to v_pk_*_f32 packed-fp32 on gfx950.
typedef float v2f __attribute__((ext_vector_type(2)));

// ---------------------------------------------------------------------------
// Single fused kernel.
// Phase 1 (per block, ~0.3 us, all 4 waves in parallel): build the fixed
//   16x16 complex unitary U cooperatively. Thread (r = t&15, c = t>>4) owns
//   element U[r][c]. Gates act on the row index only:
//     CNOT  -> intra-16-lane-group gather  (__shfl, computed source lane)
//     RY    -> partner butterfly           (__shfl_xor with mask m)
//     RZ    -> diagonal phase              (no communication)
//   Result stored once to LDS (2 KB), __syncthreads.
// Phase 2 (per thread): product state from RY(x)|0> (8 trig + 24 mul),
//   v = U s via 256 v_pk_fma_f32 with U read from LDS (wave-uniform
//   broadcast ds_read_b128 -> conflict-free, LDS pipe overlaps VALU),
//   |v|^2 + packed sign butterfly -> 4 Z-expectations.
// This removes the separate prep kernel, its launch + full-drain
// serialization, and all d_ws use.
// ---------------------------------------------------------------------------
__global__ __launch_bounds__(256) void vqc_fused(
    const float4* __restrict__ x4, const float* __restrict__ w,
    float4* __restrict__ out4) {
  const int t = threadIdx.x;
  const int r = t & 15;        // row = amplitude index
  const int c = t >> 4;        // col = input basis state
  const int lane = t & 63;
  const int grp = lane & 0x30; // 16-lane group base within the wave

  // ---------------- phase 1: distributed U build --------------------------
  float er = (r == c) ? 1.f : 0.f;
  float ei = 0.f;

#pragma unroll
  for (int layer = 0; layer < NL; ++layer) {
    // this layer's 8 angles: uniform scalar loads + quarter-rate trig,
    // hoisted ahead of the dependent gate chain
    float cy[NQ], sy[NQ], cz[NQ], sz[NQ];
#pragma unroll
    for (int q = 0; q < NQ; ++q) {
      const int k = layer * NQ + q;
      const float ty = 0.5f * w[2 * k];
      const float tz = 0.5f * w[2 * k + 1];
      cy[q] = __cosf(ty); sy[q] = __sinf(ty);
      cz[q] = __cosf(tz); sz[q] = __sinf(tz);
    }
    // CNOT ring: new(r) = old(r ^ (cbit(r) << (3-target)))
#pragma unroll
    for (int i = 0; i < NQ; ++i) {
      const int tq = (i + 1) & 3;
      const int cbit = (r >> (3 - i)) & 1;
      const int srcLane = grp | (r ^ (cbit << (3 - tq)));
      er = __shfl(er, srcLane);
      ei = __shfl(ei, srcLane);
    }
#pragma unroll
    for (int q = 0; q < NQ; ++q) {
      const int m = 8 >> q;
      // RY(q): bit0: c*self - s*partner ; bit1: c*self + s*partner
      const float pr = __shfl_xor(er, m);
      const float pi = __shfl_xor(ei, m);
      const float sgy = (r & m) ? sy[q] : -sy[q];
      er = cy[q] * er + sgy * pr;
      ei = cy[q] * ei + sgy * pi;
      // RZ(q): bit1: *(ch + i sh) ; bit0: *(ch - i sh)
      const float sgz = (r & m) ? sz[q] : -sz[q];
      const float ar = er, ai = ei;
      er = cz[q] * ar - sgz * ai;
      ei = cz[q] * ai + sgz * ar;
    }
  }

  // row-major, re/im interleaved: Ush[j*16+i] = U[j][i]
  __shared__ __align__(16) v2f Ush[DIM * DIM];
  {
    v2f e; e.x = er; e.y = ei;
    Ush[r * DIM + c] = e;  // one 16-way-conflicted ds_write_b64; once/block
  }
  __syncthreads();

  // ---------------- phase 2: per-thread batch element ----------------------
  const int b = blockIdx.x * 256 + t;
  const float4 xv = x4[b];

  const float s0 = __sinf(0.5f * xv.x), c0 = __cosf(0.5f * xv.x);
  const float s1 = __sinf(0.5f * xv.y), c1 = __cosf(0.5f * xv.y);
  const float s2 = __sinf(0.5f * xv.z), c2 = __cosf(0.5f * xv.z);
  const float s3 = __sinf(0.5f * xv.w), c3 = __cosf(0.5f * xv.w);

  // product state: idx bit3 = wire0 ... bit0 = wire3; bit=0 -> cos, 1 -> sin
  float ab[4], cd[4];
  ab[0] = c0 * c1; ab[1] = c0 * s1; ab[2] = s0 * c1; ab[3] = s0 * s1;
  cd[0] = c2 * c3; cd[1] = c2 * s3; cd[2] = s2 * c3; cd[3] = s2 * s3;
  float sv[DIM];
#pragma unroll
  for (int hi = 0; hi < 4; ++hi)
#pragma unroll
    for (int lo = 0; lo < 4; ++lo) sv[hi * 4 + lo] = ab[hi] * cd[lo];

  // v = U s packed (re,im); rows read as broadcast ds_read_b128
  const float4* U4 = (const float4*)Ush;  // U4[j*8+p] = cols 2p,2p+1 of row j
  v2f P[8];
#pragma unroll
  for (int tt = 0; tt < 8; ++tt) {
    v2f acc0 = {0.f, 0.f}, acc1 = {0.f, 0.f};
#pragma unroll
    for (int p = 0; p < 8; ++p) {
      const float4 u0 = U4[(2 * tt) * 8 + p];
      const float4 u1 = U4[(2 * tt + 1) * 8 + p];
      v2f sb0; sb0.x = sv[2 * p];     sb0.y = sv[2 * p];
      v2f sb1; sb1.x = sv[2 * p + 1]; sb1.y = sv[2 * p + 1];
      v2f a0; a0.x = u0.x; a0.y = u0.y;
      v2f b0; b0.x = u0.z; b0.y = u0.w;
      v2f a1; a1.x = u1.x; a1.y = u1.y;
      v2f b1; b1.x = u1.z; b1.y = u1.w;
      acc0 = __builtin_elementwise_fma(a0, sb0, acc0);
      acc0 = __builtin_elementwise_fma(b0, sb1, acc0);
      acc1 = __builtin_elementwise_fma(a1, sb0, acc1);
      acc1 = __builtin_elementwise_fma(b1, sb1, acc1);
    }
    const v2f q0 = acc0 * acc0, q1 = acc1 * acc1;  // v_pk_mul_f32
    P[tt].x = q0.x + q0.y;
    P[tt].y = q1.x + q1.y;
  }

  // packed sign butterfly. j bits: bit3->z0, bit2->z1, bit1->z2, bit0->z3.
  const v2f C0 = P[0] + P[1], C1 = P[2] + P[3];
  const v2f C2 = P[4] + P[5], C3 = P[6] + P[7];
  const v2f C01 = C0 + C1, C23 = C2 + C3;
  const v2f S  = C01 + C23;                      // {sum even j, sum odd j}
  const v2f D0 = C01 - C23;                      // z0 = D0.x + D0.y
  const v2f D1 = (C0 + C2) - (C1 + C3);          // z1 = D1.x + D1.y
  const v2f Ea = P[0] + P[2], Eb = P[4] + P[6];
  const v2f Oa = P[1] + P[3], Ob = P[5] + P[7];
  const v2f D2 = (Ea + Eb) - (Oa + Ob);          // z2 = D2.x + D2.y
  const float z0 = D0.x + D0.y;
  const float z1 = D1.x + D1.y;
  const float z2 = D2.x + D2.y;
  const float z3 = S.x - S.y;                    // even - odd (bit0)

  out4[b] = make_float4(z0, z1, z2, z3);
}

extern "C" void kernel_launch(void* const* d_in, const int* in_sizes, int n_in,
                              void* d_out, int out_size, void* d_ws,
                              size_t ws_size, hipStream_t stream) {
  const float* x = (const float*)d_in[0];
  const float* w = (const float*)d_in[1];
  vqc_fused<<<VQC_BATCH / 256, 256, 0, stream>>>((const float4*)x, w,
                                                 (float4*)d_out);
}